// Round 1
// baseline (216.015 us; speedup 1.0000x reference)
//
#include <hip/hip_runtime.h>

#define THREADS 256
#define MAXBLK 2048
#define EPS 1e-10
#define THRES 4.0f

__device__ __forceinline__ double wave_sum(double v) {
#pragma unroll
  for (int off = 32; off > 0; off >>= 1)
    v += __shfl_down(v, off, 64);
  return v;
}

// blockDim.x must be 256 (4 waves). Safe to call repeatedly (leading sync).
__device__ __forceinline__ double block_sum(double v, double* lds) {
  v = wave_sum(v);
  const int lane = threadIdx.x & 63;
  const int wid = threadIdx.x >> 6;
  __syncthreads();
  if (lane == 0) lds[wid] = v;
  __syncthreads();
  return lds[0] + lds[1] + lds[2] + lds[3];
}

// Pass 1: global sum / sum-of-squares -> per-block partials
__global__ void __launch_bounds__(THREADS) k_reduce1(
    const float4* __restrict__ xv, long nvec,
    const float* __restrict__ x, long n,
    double* __restrict__ pA, double* __restrict__ pB) {
  __shared__ double lds[4];
  double s = 0.0, ss = 0.0;
  const long stride = (long)gridDim.x * blockDim.x;
  const long gtid = (long)blockIdx.x * blockDim.x + threadIdx.x;
  for (long i = gtid; i < nvec; i += stride) {
    float4 v = xv[i];
    double a = v.x, b = v.y, c = v.z, d = v.w;
    s += (a + b) + (c + d);
    ss += (a * a + b * b) + (c * c + d * d);
  }
  for (long i = nvec * 4 + gtid; i < n; i += stride) {
    double a = x[i];
    s += a;
    ss += a * a;
  }
  s = block_sum(s, lds);
  ss = block_sum(ss, lds);
  if (threadIdx.x == 0) {
    pA[blockIdx.x] = s;
    pB[blockIdx.x] = ss;
  }
}

// Finalize pass 1: mean1, rsqrt(var1+eps)
__global__ void __launch_bounds__(THREADS) k_fin1(
    const double* __restrict__ pA, const double* __restrict__ pB, int nblk,
    double n, double* __restrict__ fin) {
  __shared__ double lds[4];
  double s = 0.0, ss = 0.0;
  for (int i = threadIdx.x; i < nblk; i += blockDim.x) {
    s += pA[i];
    ss += pB[i];
  }
  s = block_sum(s, lds);
  ss = block_sum(ss, lds);
  if (threadIdx.x == 0) {
    double mean1 = s / n;
    double var1 = (ss - s * s / n) / (n - 1.0);
    fin[0] = mean1;
    fin[1] = 1.0 / sqrt(var1 + EPS);
  }
}

// Pass 2: masked sum / sum-of-squares / count -> per-block partials
__global__ void __launch_bounds__(THREADS) k_reduce2(
    const float4* __restrict__ xv, long nvec,
    const float* __restrict__ x, long n,
    const double* __restrict__ fin,
    double* __restrict__ pA, double* __restrict__ pB, double* __restrict__ pC) {
  __shared__ double lds[4];
  const float m1 = (float)fin[0];
  const float r1 = (float)fin[1];
  double s = 0.0, ss = 0.0, c = 0.0;
  const long stride = (long)gridDim.x * blockDim.x;
  const long gtid = (long)blockIdx.x * blockDim.x + threadIdx.x;
  for (long i = gtid; i < nvec; i += stride) {
    float4 v = xv[i];
    float nf;
    nf = (v.x - m1) * r1;
    if (nf < THRES && nf > -THRES) { double a = v.x; s += a; ss += a * a; c += 1.0; }
    nf = (v.y - m1) * r1;
    if (nf < THRES && nf > -THRES) { double a = v.y; s += a; ss += a * a; c += 1.0; }
    nf = (v.z - m1) * r1;
    if (nf < THRES && nf > -THRES) { double a = v.z; s += a; ss += a * a; c += 1.0; }
    nf = (v.w - m1) * r1;
    if (nf < THRES && nf > -THRES) { double a = v.w; s += a; ss += a * a; c += 1.0; }
  }
  for (long i = nvec * 4 + gtid; i < n; i += stride) {
    float xf = x[i];
    float nf = (xf - m1) * r1;
    if (nf < THRES && nf > -THRES) { double a = xf; s += a; ss += a * a; c += 1.0; }
  }
  s = block_sum(s, lds);
  ss = block_sum(ss, lds);
  c = block_sum(c, lds);
  if (threadIdx.x == 0) {
    pA[blockIdx.x] = s;
    pB[blockIdx.x] = ss;
    pC[blockIdx.x] = c;
  }
}

// Finalize pass 2: mean2, rsqrt(var2+eps)
__global__ void __launch_bounds__(THREADS) k_fin2(
    const double* __restrict__ pA, const double* __restrict__ pB,
    const double* __restrict__ pC, int nblk, double* __restrict__ fin) {
  __shared__ double lds[4];
  double s = 0.0, ss = 0.0, c = 0.0;
  for (int i = threadIdx.x; i < nblk; i += blockDim.x) {
    s += pA[i];
    ss += pB[i];
    c += pC[i];
  }
  s = block_sum(s, lds);
  ss = block_sum(ss, lds);
  c = block_sum(c, lds);
  if (threadIdx.x == 0) {
    double mean2 = s / c;
    double var2 = (ss - s * s / c) / (c - 1.0);
    fin[2] = mean2;
    fin[3] = 1.0 / sqrt(var2 + EPS);
  }
}

// Pass 3: out = gamma * (x - mean2) * rsqrt(var2+eps) + beta
__global__ void __launch_bounds__(THREADS) k_apply(
    const float4* __restrict__ xv, float4* __restrict__ ov, long nvec,
    const float* __restrict__ x, float* __restrict__ o, long n,
    const double* __restrict__ fin,
    const float* __restrict__ gamma, const float* __restrict__ beta) {
  const float m2 = (float)fin[2];
  const float r2 = (float)fin[3];
  const float g = gamma[0];
  const float b = beta[0];
  const long stride = (long)gridDim.x * blockDim.x;
  const long gtid = (long)blockIdx.x * blockDim.x + threadIdx.x;
  for (long i = gtid; i < nvec; i += stride) {
    float4 v = xv[i];
    float4 t;
    t.x = g * (v.x - m2) * r2 + b;
    t.y = g * (v.y - m2) * r2 + b;
    t.z = g * (v.z - m2) * r2 + b;
    t.w = g * (v.w - m2) * r2 + b;
    ov[i] = t;
  }
  for (long i = nvec * 4 + gtid; i < n; i += stride) {
    o[i] = g * (x[i] - m2) * r2 + b;
  }
}

extern "C" void kernel_launch(void* const* d_in, const int* in_sizes, int n_in,
                              void* d_out, int out_size, void* d_ws, size_t ws_size,
                              hipStream_t stream) {
  const float* x = (const float*)d_in[0];
  const float* gamma = (const float*)d_in[1];
  const float* beta = (const float*)d_in[2];
  float* out = (float*)d_out;
  const long n = (long)in_sizes[0];
  const long nvec = n / 4;

  // Workspace layout: [0,64) finals (4 doubles), then 3 partial arrays of nblk doubles.
  int nblk = MAXBLK;
  while ((size_t)(64 + 3 * (size_t)nblk * sizeof(double)) > ws_size && nblk > 64)
    nblk >>= 1;
  double* fin = (double*)d_ws;
  double* pA = (double*)((char*)d_ws + 64);
  double* pB = pA + nblk;
  double* pC = pB + nblk;

  const float4* xv = (const float4*)x;
  float4* ov = (float4*)out;

  k_reduce1<<<nblk, THREADS, 0, stream>>>(xv, nvec, x, n, pA, pB);
  k_fin1<<<1, THREADS, 0, stream>>>(pA, pB, nblk, (double)n, fin);
  k_reduce2<<<nblk, THREADS, 0, stream>>>(xv, nvec, x, n, fin, pA, pB, pC);
  k_fin2<<<1, THREADS, 0, stream>>>(pA, pB, pC, nblk, fin);
  k_apply<<<nblk, THREADS, 0, stream>>>(xv, ov, nvec, x, out, n, fin, gamma, beta);
}

// Round 2
// 181.677 us; speedup vs baseline: 1.1890x; 1.1890x over previous
//
#include <hip/hip_runtime.h>

#define THREADS 256
#define NBLK 2048
#define ESTBLK 64
#define OUTBLK 64
#define CAP 256
#define EST_CHUNK (1 << 20)
#define EPS 1e-10
#define THRES 4.0f

typedef float vf4 __attribute__((ext_vector_type(4)));

__device__ __forceinline__ double wave_sum(double v) {
#pragma unroll
  for (int off = 32; off > 0; off >>= 1) v += __shfl_down(v, off, 64);
  return v;
}

// blockDim.x must be 256 (4 waves).
__device__ __forceinline__ double block_sum(double v, double* lds) {
  v = wave_sum(v);
  const int lane = threadIdx.x & 63;
  const int wid = threadIdx.x >> 6;
  __syncthreads();
  if (lane == 0) lds[wid] = v;
  __syncthreads();
  return lds[0] + lds[1] + lds[2] + lds[3];
}

// --- Estimate pre-pass: exact sum/ss over first EST_CHUNK elements -> per-block partials
__global__ void __launch_bounds__(THREADS) k_est(
    const float4* __restrict__ xv, long nvec_est,
    double* __restrict__ pEa, double* __restrict__ pEb) {
  __shared__ double lds[4];
  double s = 0.0, ss = 0.0;
  const long stride = (long)gridDim.x * blockDim.x;
  for (long i = (long)blockIdx.x * blockDim.x + threadIdx.x; i < nvec_est; i += stride) {
    float4 v = xv[i];
    double a = v.x, b = v.y, c = v.z, d = v.w;
    s += (a + b) + (c + d);
    ss += (a * a + b * b) + (c * c + d * d);
  }
  s = block_sum(s, lds);
  ss = block_sum(ss, lds);
  if (threadIdx.x == 0) { pEa[blockIdx.x] = s; pEb[blockIdx.x] = ss; }
}

__global__ void __launch_bounds__(THREADS) k_estfin(
    const double* __restrict__ pEa, const double* __restrict__ pEb, int nblk,
    double nest, double* __restrict__ est) {
  __shared__ double lds[4];
  double s = 0.0, ss = 0.0;
  for (int i = threadIdx.x; i < nblk; i += blockDim.x) { s += pEa[i]; ss += pEb[i]; }
  s = block_sum(s, lds);
  ss = block_sum(ss, lds);
  if (threadIdx.x == 0) {
    double m = s / nest;
    double var = (ss - s * s / nest) / (nest - 1.0);
    double sig = var > 0.0 ? sqrt(var) : 0.0;
    est[0] = m;
    est[1] = 3.0 * sig;  // candidate threshold on |x - m_hat|
  }
}

// --- Pass 1 + candidate collection
__global__ void __launch_bounds__(THREADS) k_reduce1c(
    const float4* __restrict__ xv, long nvec,
    const float* __restrict__ x, long n,
    const double* __restrict__ est,
    double* __restrict__ pA, double* __restrict__ pB,
    float* __restrict__ slices, int* __restrict__ counts) {
  __shared__ double lds[4];
  __shared__ int lcnt;
  __shared__ float lcand[CAP];
  if (threadIdx.x == 0) lcnt = 0;
  __syncthreads();
  const float mh = (float)est[0];
  const float th = (float)est[1];
  double s = 0.0, ss = 0.0;
  const long stride = (long)gridDim.x * blockDim.x;
  const long gtid = (long)blockIdx.x * blockDim.x + threadIdx.x;
  for (long i = gtid; i < nvec; i += stride) {
    float4 v = xv[i];
    double a = v.x, b = v.y, c = v.z, d = v.w;
    s += (a + b) + (c + d);
    ss += (a * a + b * b) + (c * c + d * d);
    if (fabsf(v.x - mh) > th) { int k = atomicAdd(&lcnt, 1); if (k < CAP) lcand[k] = v.x; }
    if (fabsf(v.y - mh) > th) { int k = atomicAdd(&lcnt, 1); if (k < CAP) lcand[k] = v.y; }
    if (fabsf(v.z - mh) > th) { int k = atomicAdd(&lcnt, 1); if (k < CAP) lcand[k] = v.z; }
    if (fabsf(v.w - mh) > th) { int k = atomicAdd(&lcnt, 1); if (k < CAP) lcand[k] = v.w; }
  }
  for (long i = nvec * 4 + gtid; i < n; i += stride) {
    float f = x[i];
    double a = f;
    s += a;
    ss += a * a;
    if (fabsf(f - mh) > th) { int k = atomicAdd(&lcnt, 1); if (k < CAP) lcand[k] = f; }
  }
  s = block_sum(s, lds);   // syncs make lcnt/lcand visible afterwards
  ss = block_sum(ss, lds);
  if (threadIdx.x == 0) {
    pA[blockIdx.x] = s;
    pB[blockIdx.x] = ss;
    counts[blockIdx.x] = lcnt;
  }
  int c = lcnt < CAP ? lcnt : CAP;
  for (int t = threadIdx.x; t < c; t += blockDim.x)
    slices[(size_t)blockIdx.x * CAP + t] = lcand[t];
}

// --- Plain pass 1 (fallback, no collection)
__global__ void __launch_bounds__(THREADS) k_reduce1(
    const float4* __restrict__ xv, long nvec,
    const float* __restrict__ x, long n,
    double* __restrict__ pA, double* __restrict__ pB) {
  __shared__ double lds[4];
  double s = 0.0, ss = 0.0;
  const long stride = (long)gridDim.x * blockDim.x;
  const long gtid = (long)blockIdx.x * blockDim.x + threadIdx.x;
  for (long i = gtid; i < nvec; i += stride) {
    float4 v = xv[i];
    double a = v.x, b = v.y, c = v.z, d = v.w;
    s += (a + b) + (c + d);
    ss += (a * a + b * b) + (c * c + d * d);
  }
  for (long i = nvec * 4 + gtid; i < n; i += stride) {
    double a = x[i];
    s += a;
    ss += a * a;
  }
  s = block_sum(s, lds);
  ss = block_sum(ss, lds);
  if (threadIdx.x == 0) { pA[blockIdx.x] = s; pB[blockIdx.x] = ss; }
}

// --- Finalize pass 1: mean1/r1, coverage check -> flag
__global__ void __launch_bounds__(THREADS) k_fin1(
    const double* __restrict__ pA, const double* __restrict__ pB, int nblk,
    const int* __restrict__ counts, const double* __restrict__ est, int have_cand,
    double n, double* __restrict__ fin, int* __restrict__ flag) {
  __shared__ double lds[4];
  __shared__ int lmx[4];
  double s = 0.0, ss = 0.0;
  for (int i = threadIdx.x; i < nblk; i += blockDim.x) { s += pA[i]; ss += pB[i]; }
  s = block_sum(s, lds);
  ss = block_sum(ss, lds);
  int mx = 0;
  if (have_cand) {
    for (int i = threadIdx.x; i < nblk; i += blockDim.x) {
      int c = counts[i];
      mx = mx > c ? mx : c;
    }
  }
#pragma unroll
  for (int off = 32; off > 0; off >>= 1) {
    int o = __shfl_down(mx, off, 64);
    mx = mx > o ? mx : o;
  }
  __syncthreads();
  if ((threadIdx.x & 63) == 0) lmx[threadIdx.x >> 6] = mx;
  __syncthreads();
  if (threadIdx.x == 0) {
    int maxcnt = lmx[0] > lmx[1] ? lmx[0] : lmx[1];
    int m23 = lmx[2] > lmx[3] ? lmx[2] : lmx[3];
    maxcnt = maxcnt > m23 ? maxcnt : m23;
    double mean1 = s / n;
    double var1 = (ss - s * s / n) / (n - 1.0);
    double sig1 = var1 > 0.0 ? sqrt(var1) : 0.0;
    fin[0] = mean1;
    fin[1] = 1.0 / sqrt(var1 + EPS);
    fin[4] = s;
    fin[5] = ss;
    int ok = 0;
    if (have_cand) {
      // candidates (|x-m_hat| > thr_hat) must cover every fp32-normalized |z| >= 4
      double thr_hat = est[1];
      ok = (maxcnt <= CAP) && (thr_hat > 0.0) &&
           (thr_hat < 4.0 * sig1 * (1.0 - 1e-4) - fabs(mean1 - est[0]));
    }
    *flag = ok;
  }
}

// --- Outlier reduction over the compact candidate buffer
__global__ void __launch_bounds__(THREADS) k_outlier(
    const float* __restrict__ slices, const int* __restrict__ counts, int nslices,
    const int* __restrict__ flag, const double* __restrict__ fin,
    double* __restrict__ pD, double* __restrict__ pE, double* __restrict__ pF) {
  if (!*flag) return;
  __shared__ double lds[4];
  const float m1 = (float)fin[0];
  const float r1 = (float)fin[1];
  double s = 0.0, ss = 0.0, c = 0.0;
  const long total = (long)nslices * CAP;
  const long stride = (long)gridDim.x * blockDim.x;
  for (long j = (long)blockIdx.x * blockDim.x + threadIdx.x; j < total; j += stride) {
    int sl = (int)(j / CAP);
    int t = (int)(j % CAP);
    int cnt = counts[sl];
    cnt = cnt < CAP ? cnt : CAP;
    if (t < cnt) {
      float v = slices[j];
      float nf = (v - m1) * r1;
      if (!(nf < THRES && nf > -THRES)) {  // exact same strict rule as reference
        double a = v;
        s += a;
        ss += a * a;
        c += 1.0;
      }
    }
  }
  s = block_sum(s, lds);
  ss = block_sum(ss, lds);
  c = block_sum(c, lds);
  if (threadIdx.x == 0) { pD[blockIdx.x] = s; pE[blockIdx.x] = ss; pF[blockIdx.x] = c; }
}

// --- Full pass 2 (fallback; early-exits when candidate path is valid)
__global__ void __launch_bounds__(THREADS) k_reduce2f(
    const float4* __restrict__ xv, long nvec,
    const float* __restrict__ x, long n,
    const double* __restrict__ fin, const int* __restrict__ flag,
    double* __restrict__ pA, double* __restrict__ pB, double* __restrict__ pC) {
  if (*flag) return;
  __shared__ double lds[4];
  const float m1 = (float)fin[0];
  const float r1 = (float)fin[1];
  double s = 0.0, ss = 0.0, c = 0.0;
  const long stride = (long)gridDim.x * blockDim.x;
  const long gtid = (long)blockIdx.x * blockDim.x + threadIdx.x;
  for (long i = gtid; i < nvec; i += stride) {
    float4 v = xv[i];
    float nf;
    nf = (v.x - m1) * r1;
    if (nf < THRES && nf > -THRES) { double a = v.x; s += a; ss += a * a; c += 1.0; }
    nf = (v.y - m1) * r1;
    if (nf < THRES && nf > -THRES) { double a = v.y; s += a; ss += a * a; c += 1.0; }
    nf = (v.z - m1) * r1;
    if (nf < THRES && nf > -THRES) { double a = v.z; s += a; ss += a * a; c += 1.0; }
    nf = (v.w - m1) * r1;
    if (nf < THRES && nf > -THRES) { double a = v.w; s += a; ss += a * a; c += 1.0; }
  }
  for (long i = nvec * 4 + gtid; i < n; i += stride) {
    float xf = x[i];
    float nf = (xf - m1) * r1;
    if (nf < THRES && nf > -THRES) { double a = xf; s += a; ss += a * a; c += 1.0; }
  }
  s = block_sum(s, lds);
  ss = block_sum(ss, lds);
  c = block_sum(c, lds);
  if (threadIdx.x == 0) { pA[blockIdx.x] = s; pB[blockIdx.x] = ss; pC[blockIdx.x] = c; }
}

// --- Finalize pass 2 (either path)
__global__ void __launch_bounds__(THREADS) k_fin2(
    const double* __restrict__ pA, const double* __restrict__ pB,
    const double* __restrict__ pC, int nblk,
    const double* __restrict__ pD, const double* __restrict__ pE,
    const double* __restrict__ pF, int noblk,
    const int* __restrict__ flag, double n, double* __restrict__ fin) {
  __shared__ double lds[4];
  double s, ss, c;
  if (*flag) {
    double so = 0.0, sso = 0.0, co = 0.0;
    for (int i = threadIdx.x; i < noblk; i += blockDim.x) { so += pD[i]; sso += pE[i]; co += pF[i]; }
    so = block_sum(so, lds);
    sso = block_sum(sso, lds);
    co = block_sum(co, lds);
    s = fin[4] - so;
    ss = fin[5] - sso;
    c = n - co;
  } else {
    double s2 = 0.0, ss2 = 0.0, c2 = 0.0;
    for (int i = threadIdx.x; i < nblk; i += blockDim.x) { s2 += pA[i]; ss2 += pB[i]; c2 += pC[i]; }
    s = block_sum(s2, lds);
    ss = block_sum(ss2, lds);
    c = block_sum(c2, lds);
  }
  if (threadIdx.x == 0) {
    double mean2 = s / c;
    double var2 = (ss - s * s / c) / (c - 1.0);
    fin[2] = mean2;
    fin[3] = 1.0 / sqrt(var2 + EPS);
  }
}

// --- Pass 3: affine apply; non-temporal stores so x stays L3-resident
__global__ void __launch_bounds__(THREADS) k_apply(
    const float4* __restrict__ xv, float4* __restrict__ ov, long nvec,
    const float* __restrict__ x, float* __restrict__ o, long n,
    const double* __restrict__ fin,
    const float* __restrict__ gamma, const float* __restrict__ beta) {
  const float m2 = (float)fin[2];
  const float r2 = (float)fin[3];
  const float g = gamma[0];
  const float b = beta[0];
  const long stride = (long)gridDim.x * blockDim.x;
  const long gtid = (long)blockIdx.x * blockDim.x + threadIdx.x;
  for (long i = gtid; i < nvec; i += stride) {
    float4 v = xv[i];
    vf4 t;
    t.x = g * (v.x - m2) * r2 + b;
    t.y = g * (v.y - m2) * r2 + b;
    t.z = g * (v.z - m2) * r2 + b;
    t.w = g * (v.w - m2) * r2 + b;
    __builtin_nontemporal_store(t, (vf4*)&ov[i]);
  }
  for (long i = nvec * 4 + gtid; i < n; i += stride) {
    float t = g * (x[i] - m2) * r2 + b;
    __builtin_nontemporal_store(t, &o[i]);
  }
}

extern "C" void kernel_launch(void* const* d_in, const int* in_sizes, int n_in,
                              void* d_out, int out_size, void* d_ws, size_t ws_size,
                              hipStream_t stream) {
  const float* x = (const float*)d_in[0];
  const float* gamma = (const float*)d_in[1];
  const float* beta = (const float*)d_in[2];
  float* out = (float*)d_out;
  const long n = (long)in_sizes[0];
  const long nvec = n / 4;
  const float4* xv = (const float4*)x;
  float4* ov = (float4*)out;

  // Workspace layout (candidate path)
  char* base = (char*)d_ws;
  double* fin = (double*)base;            // 8 doubles
  int* flag = (int*)(base + 64);
  double* est = (double*)(base + 128);    // 2 doubles
  double* pA = (double*)(base + 192);
  double* pB = pA + NBLK;
  double* pC = pB + NBLK;
  double* pEa = pC + NBLK;
  double* pEb = pEa + ESTBLK;
  double* pD = pEb + ESTBLK;
  double* pE = pD + OUTBLK;
  double* pF = pE + OUTBLK;
  int* counts = (int*)(pF + OUTBLK);
  float* slices = (float*)(counts + NBLK);
  size_t needed = (size_t)((char*)(slices + (size_t)NBLK * CAP) - base);

  bool cand = (ws_size >= needed) && (n >= (long)(1 << 22));

  if (cand) {
    k_est<<<ESTBLK, THREADS, 0, stream>>>(xv, (long)(EST_CHUNK / 4), pEa, pEb);
    k_estfin<<<1, THREADS, 0, stream>>>(pEa, pEb, ESTBLK, (double)EST_CHUNK, est);
    k_reduce1c<<<NBLK, THREADS, 0, stream>>>(xv, nvec, x, n, est, pA, pB, slices, counts);
    k_fin1<<<1, THREADS, 0, stream>>>(pA, pB, NBLK, counts, est, 1, (double)n, fin, flag);
    k_outlier<<<OUTBLK, THREADS, 0, stream>>>(slices, counts, NBLK, flag, fin, pD, pE, pF);
    k_reduce2f<<<NBLK, THREADS, 0, stream>>>(xv, nvec, x, n, fin, flag, pA, pB, pC);
    k_fin2<<<1, THREADS, 0, stream>>>(pA, pB, pC, NBLK, pD, pE, pF, OUTBLK, flag, (double)n, fin);
    k_apply<<<NBLK, THREADS, 0, stream>>>(xv, ov, nvec, x, out, n, fin, gamma, beta);
  } else {
    // Fallback: round-1 pipeline in a minimal layout
    int nblk = NBLK;
    while ((size_t)(192 + 3 * (size_t)nblk * sizeof(double)) > ws_size && nblk > 64) nblk >>= 1;
    double* fA = (double*)(base + 192);
    double* fB = fA + nblk;
    double* fC = fB + nblk;
    k_reduce1<<<nblk, THREADS, 0, stream>>>(xv, nvec, x, n, fA, fB);
    k_fin1<<<1, THREADS, 0, stream>>>(fA, fB, nblk, nullptr, nullptr, 0, (double)n, fin, flag);
    k_reduce2f<<<nblk, THREADS, 0, stream>>>(xv, nvec, x, n, fin, flag, fA, fB, fC);
    k_fin2<<<1, THREADS, 0, stream>>>(fA, fB, fC, nblk, fA, fB, fC, nblk, flag, (double)n, fin);
    k_apply<<<nblk, THREADS, 0, stream>>>(xv, ov, nvec, x, out, n, fin, gamma, beta);
  }
}